// Round 1
// baseline (4062.577 us; speedup 1.0000x reference)
//
#include <hip/hip_runtime.h>

// SLAYER SNN forward on MI355X.
// Layout everywhere: (b, c, h, w, t) with t innermost, T=300 (75 float4 quads).
// Spikes stored as float32 0/1. All math fp32 (matches jnp.float32 reference).
//
// ws layout (floats):
//   sA = ws                  : 33,292,800  (s1 / s3 / s5 / s7)
//   sB = sA + 33,292,800     :  8,323,200  (s2 / s4 / s6)
//   U  = sB +  8,323,200     : 16,646,400  (membrane inputs for L3/L5/L7/L8)
// total ~233 MB.

#define TQ 75     // 300 / 4
#define TT 300

// float32-rounded IIR constants (match np.exp/np.e via jnp.float32)
#define A1 0.9048374180359595f   // exp(-1/10)
#define C1 0.2718281828459045f   // e/10
#define A2 0.36787944117144233f  // exp(-1)
#define C2 2.718281828459045f    // e
#define KREF (20.0f * C2)        // SCALE_REF*THETA*c_ref
#define THETA_F 10.0f

struct IIR {
  float p1, q1, p2, q2;
  __device__ IIR() : p1(0.f), q1(0.f), p2(0.f), q2(0.f) {}
  __device__ inline float step(float xin) {
    // psp: q = a*q + a*p (old p); y = c*q; p = a*p + x
    q1 = A1 * q1 + A1 * p1;
    float y = C1 * q1;
    p1 = A1 * p1 + xin;
    // spike: q2 = a*q2 + a*p2 (old p2); u = y - K*q2; s = u>=theta; p2 = a*p2 + s
    q2 = A2 * q2 + A2 * p2;
    float u = y - KREF * q2;
    float s = (u >= THETA_F) ? 1.0f : 0.0f;
    p2 = A2 * p2 + s;
    return s;
  }
};

// ---------------- Layer 1: conv(2->24, k5, pad2) fused with psp+spike ----------------
// grid (5, 24, 4); one thread per output neuron (y,x) of one (b,co).
__global__ __launch_bounds__(256) void conv1_ps(const float* __restrict__ sin,
                                                const float* __restrict__ w,
                                                float* __restrict__ out) {
  const int b = blockIdx.z, co = blockIdx.y;
  __shared__ float wl[50];
  if (threadIdx.x < 50) wl[threadIdx.x] = w[co * 50 + threadIdx.x];
  __syncthreads();
  int n = blockIdx.x * 256 + threadIdx.x;
  if (n >= 34 * 34) return;
  int y = n / 34, x = n % 34;
  float* op = out + (((b * 24 + co) * 34 + y) * 34 + x) * TT;
  IIR st;
  for (int tq = 0; tq < TQ; ++tq) {
    float4 acc = {0.f, 0.f, 0.f, 0.f};
    for (int ci = 0; ci < 2; ++ci) {
      for (int dy = 0; dy < 5; ++dy) {
        int iy = y + dy - 2;
        if (iy < 0 || iy >= 34) continue;
        const float* rp = sin + (((b * 2 + ci) * 34 + iy) * 34) * TT + tq * 4;
        const float* wp = wl + ci * 25 + dy * 5;
#pragma unroll
        for (int dx = 0; dx < 5; ++dx) {
          int ix = x + dx - 2;
          if (ix < 0 || ix >= 34) continue;
          float4 v = *(const float4*)(rp + ix * TT);
          float wv = wp[dx];
          acc.x += wv * v.x; acc.y += wv * v.y; acc.z += wv * v.z; acc.w += wv * v.w;
        }
      }
    }
    float4 s4;
    s4.x = st.step(acc.x); s4.y = st.step(acc.y);
    s4.z = st.step(acc.z); s4.w = st.step(acc.w);
    *(float4*)(op + tq * 4) = s4;
  }
}

// ---------------- 3x3 conv (pad 1), per-timestep parallel ----------------
// grid (HW, Cout, B); block covers (x, tq) flattened.
template <int CIN, int HW>
__global__ __launch_bounds__(256) void conv3x3(const float* __restrict__ sp,
                                               const float* __restrict__ w,
                                               float* __restrict__ U) {
  const int y = blockIdx.x, co = blockIdx.y, b = blockIdx.z;
  const int COUT = gridDim.y;
  __shared__ float wl[CIN * 9];
  for (int i = threadIdx.x; i < CIN * 9; i += 256) wl[i] = w[co * CIN * 9 + i];
  __syncthreads();
  const int NE = HW * TQ;
  for (int e = threadIdx.x; e < NE; e += 256) {
    int x = e / TQ, tq = e % TQ;
    float4 acc = {0.f, 0.f, 0.f, 0.f};
    for (int ci = 0; ci < CIN; ++ci) {
#pragma unroll
      for (int dy = 0; dy < 3; ++dy) {
        int iy = y + dy - 1;
        if (iy < 0 || iy >= HW) continue;
        const float* rp = sp + (((b * CIN + ci) * HW + iy) * HW) * TT + tq * 4;
        const float* wp = wl + ci * 9 + dy * 3;
#pragma unroll
        for (int dx = 0; dx < 3; ++dx) {
          int ix = x + dx - 1;
          if (ix < 0 || ix >= HW) continue;
          float4 v = *(const float4*)(rp + ix * TT);
          float wv = wp[dx];
          acc.x += wv * v.x; acc.y += wv * v.y; acc.z += wv * v.z; acc.w += wv * v.w;
        }
      }
    }
    float* up = U + (((b * COUT + co) * HW + y) * HW + x) * TT;
    *(float4*)(up + tq * 4) = acc;
  }
}

// ---------------- psp+spike over a dense U buffer ----------------
__global__ __launch_bounds__(256) void psp_spike(const float* __restrict__ U,
                                                 float* __restrict__ out, int N) {
  int n = blockIdx.x * 256 + threadIdx.x;
  if (n >= N) return;
  const float* up = U + (long)n * TT;
  float* op = out + (long)n * TT;
  IIR st;
  for (int tq = 0; tq < TQ; ++tq) {
    float4 v = *(const float4*)(up + tq * 4);
    float4 s4;
    s4.x = st.step(v.x); s4.y = st.step(v.y);
    s4.z = st.step(v.z); s4.w = st.step(v.w);
    *(float4*)(op + tq * 4) = s4;
  }
}

// ---------------- 2x2 sum-pool (x 11.0) fused with psp+spike ----------------
template <int C, int HIN, int HOUT>
__global__ __launch_bounds__(256) void pool_ps(const float* __restrict__ sp,
                                               float* __restrict__ out, int N) {
  int n = blockIdx.x * 256 + threadIdx.x;
  if (n >= N) return;
  int x2 = n % HOUT;
  int t1 = n / HOUT;
  int y2 = t1 % HOUT;
  int t2 = t1 / HOUT;
  int c = t2 % C;
  int b = t2 / C;
  int r0 = 2 * y2, r1 = 2 * y2 + 1;
  int c0 = 2 * x2, c1 = 2 * x2 + 1;
  const float* base = sp + ((long)(b * C + c) * HIN) * HIN * TT;
  const float* p00 = base + (r0 * HIN + c0) * TT;
  const float* p01 = (c1 < HIN) ? base + (r0 * HIN + c1) * TT : nullptr;
  const float* p10 = (r1 < HIN) ? base + (r1 * HIN + c0) * TT : nullptr;
  const float* p11 = (r1 < HIN && c1 < HIN) ? base + (r1 * HIN + c1) * TT : nullptr;
  float* op = out + (long)n * TT;
  IIR st;
  for (int tq = 0; tq < TQ; ++tq) {
    float4 a = *(const float4*)(p00 + tq * 4);
    if (p01) { float4 v = *(const float4*)(p01 + tq * 4); a.x += v.x; a.y += v.y; a.z += v.z; a.w += v.w; }
    if (p10) { float4 v = *(const float4*)(p10 + tq * 4); a.x += v.x; a.y += v.y; a.z += v.z; a.w += v.w; }
    if (p11) { float4 v = *(const float4*)(p11 + tq * 4); a.x += v.x; a.y += v.y; a.z += v.z; a.w += v.w; }
    float4 s4;
    s4.x = st.step(11.0f * a.x); s4.y = st.step(11.0f * a.y);
    s4.z = st.step(11.0f * a.z); s4.w = st.step(11.0f * a.w);
    *(float4*)(op + tq * 4) = s4;
  }
}

// ---------------- dense layer: U[b,o,t] = sum_k W[o,k] * S[b,k,t] ----------------
// one thread per (b,o,tq)
__global__ __launch_bounds__(256) void dense(const float* __restrict__ S,
                                             const float* __restrict__ W,
                                             float* __restrict__ U,
                                             int O, int K, int Ntot) {
  int id = blockIdx.x * 256 + threadIdx.x;
  if (id >= Ntot) return;
  int tq = id % TQ;
  int bo = id / TQ;
  int o = bo % O;
  int b = bo / O;
  const float* sp = S + (long)b * K * TT + tq * 4;
  const float* wp = W + (long)o * K;
  float4 acc = {0.f, 0.f, 0.f, 0.f};
  for (int k = 0; k < K; ++k) {
    float4 v = *(const float4*)(sp + (long)k * TT);
    float wv = wp[k];
    acc.x += wv * v.x; acc.y += wv * v.y; acc.z += wv * v.z; acc.w += wv * v.w;
  }
  float* up = U + (long)bo * TT + tq * 4;
  *(float4*)up = acc;
}

extern "C" void kernel_launch(void* const* d_in, const int* in_sizes, int n_in,
                              void* d_out, int out_size, void* d_ws, size_t ws_size,
                              hipStream_t stream) {
  const float* s_in = (const float*)d_in[0];
  const float* Wc1  = (const float*)d_in[1];
  const float* Wc2  = (const float*)d_in[2];
  const float* Wc3  = (const float*)d_in[3];
  const float* Wd4a = (const float*)d_in[4];
  const float* Wd4b = (const float*)d_in[5];

  float* sA = (float*)d_ws;                 // 33,292,800 floats
  float* sB = sA + 33292800;                // 8,323,200 floats
  float* U  = sB + 8323200;                 // 16,646,400 floats

  // L1: conv(2->24,k5,p2)+psp+spike -> sA (4,24,34,34,300)
  conv1_ps<<<dim3(5, 24, 4), 256, 0, stream>>>(s_in, Wc1, sA);
  // L2: pool 34->17 +psp+spike -> sB (4,24,17,17,300)
  pool_ps<24, 34, 17><<<(27744 + 255) / 256, 256, 0, stream>>>(sA, sB, 27744);
  // L3: conv(24->48,k3,p1) -> U ; psp+spike -> sA (4,48,17,17,300)
  conv3x3<24, 17><<<dim3(17, 48, 4), 256, 0, stream>>>(sB, Wc2, U);
  psp_spike<<<(55488 + 255) / 256, 256, 0, stream>>>(U, sA, 55488);
  // L4: pool 17->9 -> sB (4,48,9,9,300)
  pool_ps<48, 17, 9><<<(15552 + 255) / 256, 256, 0, stream>>>(sA, sB, 15552);
  // L5: conv(48->96,k3,p1) -> U ; psp+spike -> sA (4,96,9,9,300)
  conv3x3<48, 9><<<dim3(9, 96, 4), 256, 0, stream>>>(sB, Wc3, U);
  psp_spike<<<(31104 + 255) / 256, 256, 0, stream>>>(U, sA, 31104);
  // L6: pool 9->5 -> sB (4,96,5,5,300)
  pool_ps<96, 9, 5><<<(9600 + 255) / 256, 256, 0, stream>>>(sA, sB, 9600);
  // L7: dense 2400->256 -> U ; psp+spike -> sA (4,256,300)
  dense<<<(76800 + 255) / 256, 256, 0, stream>>>(sB, Wd4a, U, 256, 2400, 76800);
  psp_spike<<<4, 256, 0, stream>>>(U, sA, 1024);
  // L8: dense 256->10 -> U ; psp+spike -> d_out (4,10,300)
  dense<<<(3000 + 255) / 256, 256, 0, stream>>>(sA, Wd4b, U, 10, 256, 3000);
  psp_spike<<<1, 256, 0, stream>>>(U, (float*)d_out, 40);
}

// Round 2
// 1645.923 us; speedup vs baseline: 2.4683x; 2.4683x over previous
//
#include <hip/hip_runtime.h>

// SLAYER SNN forward, round 2: TIME-MAJOR layout [t][b][c][h][w].
// - IIR (psp+spike) kernels: lane-contiguous over neurons -> coalesced, in-place.
// - Convs: per-timestep 2D conv; block per (t,b) [L5: (2t, b)], input tile in LDS,
//   wave-uniform output-channel group -> weights via scalar loads, VALU-bound.
// - dense7: 4 rows staged in LDS, transposed weights read as coalesced float4.
// All fp32, bit-exact IIR ordering vs reference.

#define TT 300

// float32-rounded IIR constants
#define A1 0.9048374180359595f   // exp(-1/10)
#define C1 0.2718281828459045f   // e/10
#define A2 0.36787944117144233f  // exp(-1)
#define C2 2.718281828459045f    // e
#define KREF (20.0f * C2)
#define THETA_F 10.0f

struct IIR {
  float p1, q1, p2, q2;
  __device__ IIR() : p1(0.f), q1(0.f), p2(0.f), q2(0.f) {}
  __device__ inline float step(float xin) {
    q1 = A1 * q1 + A1 * p1;
    float y = C1 * q1;
    p1 = A1 * p1 + xin;
    q2 = A2 * q2 + A2 * p2;
    float u = y - KREF * q2;
    float s = (u >= THETA_F) ? 1.0f : 0.0f;
    p2 = A2 * p2 + s;
    return s;
  }
};

// ---------------- generic tiled transpose: in[R][C] -> out[C][R] ----------------
__global__ __launch_bounds__(256) void transpose_rc(const float* __restrict__ in,
                                                    float* __restrict__ out,
                                                    int R, int C) {
  __shared__ float tile[64][65];
  int c0 = blockIdx.x * 64, r0 = blockIdx.y * 64;
  int tx = threadIdx.x & 63, ty = threadIdx.x >> 6;
  for (int i = ty; i < 64; i += 4) {
    int r = r0 + i, c = c0 + tx;
    if (r < R && c < C) tile[i][tx] = in[(long)r * C + c];
  }
  __syncthreads();
  for (int i = ty; i < 64; i += 4) {
    int c = c0 + i, r = r0 + tx;
    if (c < C && r < R) out[(long)c * R + r] = tile[tx][i];
  }
}

// ---------------- per-timestep direct conv, time-major ----------------
// S: [T][B][CIN][HW][HW], W: [CO][CIN][KS][KS], U: [T][B][CO][HW][HW]
// block = 256 threads; wave w owns channels [w*NCO, (w+1)*NCO); lane = pixel.
template <int CIN, int HW, int KS, int PAD, int CO, int NCO, int NT>
__global__ __launch_bounds__(256) void conv_tm(const float* __restrict__ S,
                                               const float* __restrict__ W,
                                               float* __restrict__ U) {
  constexpr int PW = HW + 2 * PAD;
  constexpr int TILE = CIN * PW * PW;
  constexpr int NPIX = NT * HW * HW;
  constexpr int NITER = (NPIX + 63) / 64;
  __shared__ float lin[NT * TILE];
  const int t0 = blockIdx.x * NT, b = blockIdx.y, B = gridDim.y;

  for (int i = threadIdx.x; i < NT * TILE; i += 256) lin[i] = 0.f;
  __syncthreads();
  for (int tt = 0; tt < NT; ++tt) {
    const float* src = S + ((long)(t0 + tt) * B + b) * (CIN * HW * HW);
    for (int i = threadIdx.x; i < CIN * HW * HW; i += 256) {
      int ci = i / (HW * HW), r = i % (HW * HW);
      int iy = r / HW, ix = r % HW;
      lin[tt * TILE + (ci * PW + iy + PAD) * PW + (ix + PAD)] = src[i];
    }
  }
  __syncthreads();

  const int lane = threadIdx.x & 63;
  const int co0 = __builtin_amdgcn_readfirstlane(threadIdx.x >> 6) * NCO;

  for (int it = 0; it < NITER; ++it) {
    int s = lane + 64 * it;
    bool act = s < NPIX;
    int ss = act ? s : 0;
    int tt = (NT > 1) ? ss / (HW * HW) : 0;
    int p = (NT > 1) ? ss % (HW * HW) : ss;
    int y = p / HW, x = p % HW;
    const float* base = lin + tt * TILE + y * PW + x;
    float acc[NCO];
#pragma unroll
    for (int j = 0; j < NCO; ++j) acc[j] = 0.f;
    for (int ci = 0; ci < CIN; ++ci) {
      const float* bp = base + ci * (PW * PW);
      const float* wp = W + (long)co0 * (CIN * KS * KS) + ci * (KS * KS);
#pragma unroll
      for (int dy = 0; dy < KS; ++dy)
#pragma unroll
        for (int dx = 0; dx < KS; ++dx) {
          float v = bp[dy * PW + dx];
#pragma unroll
          for (int j = 0; j < NCO; ++j)
            acc[j] += wp[j * (CIN * KS * KS) + dy * KS + dx] * v;
        }
    }
    if (act) {
      float* up = U + (((long)(t0 + tt) * B + b) * CO + co0) * (HW * HW) + p;
#pragma unroll
      for (int j = 0; j < NCO; ++j) up[j * (HW * HW)] = acc[j];
    }
  }
}

// ---------------- psp+spike, time-major, IN-PLACE ----------------
__global__ __launch_bounds__(256) void psp_spike_tm(float* io, int N) {
  int n = blockIdx.x * 256 + threadIdx.x;
  if (n >= N) return;
  IIR st;
  for (int t = 0; t < TT; ++t) {
    long idx = (long)t * N + n;
    io[idx] = st.step(io[idx]);
  }
}

// ---------------- 2x2 sum-pool (x11.0) + psp+spike, time-major ----------------
template <int C, int HIN, int HOUT>
__global__ __launch_bounds__(256) void pool_ps_tm(const float* __restrict__ sp,
                                                  float* __restrict__ out, int B) {
  const int NOUT = B * C * HOUT * HOUT;
  int n = blockIdx.x * 256 + threadIdx.x;
  if (n >= NOUT) return;
  int x = n % HOUT;
  int y = (n / HOUT) % HOUT;
  int c = (n / (HOUT * HOUT)) % C;
  int b = n / (C * HOUT * HOUT);
  bool hr = 2 * y + 1 < HIN, hc = 2 * x + 1 < HIN;
  const float* base = sp + ((long)b * C + c) * (HIN * HIN) + (2 * y) * HIN + 2 * x;
  const long SIN = (long)B * C * HIN * HIN;
  const long SOUT = NOUT;
  IIR st;
  for (int t = 0; t < TT; ++t) {
    const float* p = base + t * SIN;
    float a = p[0];
    if (hc) a += p[1];
    if (hr) {
      a += p[HIN];
      if (hc) a += p[HIN + 1];
    }
    out[t * SOUT + n] = st.step(11.0f * a);
  }
}

// ---------------- dense7: U[row][o] = sum_k S[row][k] * Wt[k][o] ----------------
// rows = 1200 (t*4+b), K=2400, O=256. Block: 4 rows, thread (r=tid/64, o4=(tid&63)*4).
__global__ __launch_bounds__(256) void dense7(const float* __restrict__ S,
                                              const float* __restrict__ Wt,
                                              float* __restrict__ U) {
  __shared__ float srow[4 * 2400];
  int r0 = blockIdx.x * 4;
  const float* src = S + (long)r0 * 2400;
  for (int i = threadIdx.x; i < 9600; i += 256) srow[i] = src[i];
  __syncthreads();
  int r = __builtin_amdgcn_readfirstlane(threadIdx.x >> 6);
  int o = (threadIdx.x & 63) * 4;
  const float* sr = srow + r * 2400;
  float4 acc = {0.f, 0.f, 0.f, 0.f};
  for (int k = 0; k < 2400; ++k) {
    float a = sr[k];
    float4 w = *(const float4*)(Wt + (long)k * 256 + o);
    acc.x += a * w.x; acc.y += a * w.y; acc.z += a * w.z; acc.w += a * w.w;
  }
  *(float4*)(U + (long)(r0 + r) * 256 + o) = acc;
}

// ---------------- dense8: U[row][o] = sum_k S[row][k] * W[o][k] ----------------
__global__ __launch_bounds__(256) void dense8(const float* __restrict__ S,
                                              const float* __restrict__ W,
                                              float* __restrict__ U) {
  int id = blockIdx.x * 256 + threadIdx.x;
  if (id >= 12000) return;
  int o = id % 10, row = id / 10;
  const float* sr = S + (long)row * 256;
  const float* wr = W + o * 256;
  float acc = 0.f;
  for (int k = 0; k < 256; ++k) acc += sr[k] * wr[k];
  U[id] = acc;
}

// ---------------- final psp+spike with transpose to (B,10,T) ----------------
__global__ void psp8_out(const float* __restrict__ U, float* __restrict__ out) {
  int n = threadIdx.x;
  if (n >= 40) return;
  IIR st;
  for (int t = 0; t < TT; ++t) out[n * TT + t] = st.step(U[t * 40 + n]);
}

extern "C" void kernel_launch(void* const* d_in, const int* in_sizes, int n_in,
                              void* d_out, int out_size, void* d_ws, size_t ws_size,
                              hipStream_t stream) {
  const float* s_in = (const float*)d_in[0];
  const float* Wc1  = (const float*)d_in[1];
  const float* Wc2  = (const float*)d_in[2];
  const float* Wc3  = (const float*)d_in[3];
  const float* Wd4a = (const float*)d_in[4];
  const float* Wd4b = (const float*)d_in[5];

  float* Buf1 = (float*)d_ws;            // 33,292,800 floats
  float* Buf2 = Buf1 + 33292800;
  float* s2 = Buf2;                      //  8,323,200
  float* s4 = Buf2 + 8323200;            //  4,665,600
  float* Wt = Buf2 + 12988800;           //    614,400
  float* U7 = Buf2 + 13603200;           //    307,200 (becomes s7 in-place)
  float* T0 = Buf2 + 13910400;           //  2,774,400 (time-major input)
  float* s6 = Buf2;                      //  2,880,000 (reuses s2 region, s2 dead)
  float* U8 = Buf1;                      //     12,000 (Buf1 dead by then)

  // input (9248 rows x 300 cols) -> time-major; Wd4a (256 x 2400) -> k-major
  transpose_rc<<<dim3(5, 145), 256, 0, stream>>>(s_in, T0, 9248, 300);
  transpose_rc<<<dim3(38, 4), 256, 0, stream>>>(Wd4a, Wt, 256, 2400);

  // L1: conv 2->24 k5 p2 ; psp+spike in place
  conv_tm<2, 34, 5, 2, 24, 6, 1><<<dim3(300, 4), 256, 0, stream>>>(T0, Wc1, Buf1);
  psp_spike_tm<<<434, 256, 0, stream>>>(Buf1, 110976);
  // L2: pool 34->17 + IIR
  pool_ps_tm<24, 34, 17><<<109, 256, 0, stream>>>(Buf1, s2, 4);
  // L3: conv 24->48 k3 p1 ; psp in place
  conv_tm<24, 17, 3, 1, 48, 12, 1><<<dim3(300, 4), 256, 0, stream>>>(s2, Wc2, Buf1);
  psp_spike_tm<<<217, 256, 0, stream>>>(Buf1, 55488);
  // L4: pool 17->9 + IIR
  pool_ps_tm<48, 17, 9><<<61, 256, 0, stream>>>(Buf1, s4, 4);
  // L5: conv 48->96 k3 p1 (2 timesteps/block) ; psp in place
  conv_tm<48, 9, 3, 1, 96, 24, 2><<<dim3(150, 4), 256, 0, stream>>>(s4, Wc3, Buf1);
  psp_spike_tm<<<122, 256, 0, stream>>>(Buf1, 31104);
  // L6: pool 9->5 + IIR
  pool_ps_tm<96, 9, 5><<<38, 256, 0, stream>>>(Buf1, s6, 4);
  // L7: dense 2400->256 ; psp in place
  dense7<<<300, 256, 0, stream>>>(s6, Wt, U7);
  psp_spike_tm<<<4, 256, 0, stream>>>(U7, 1024);
  // L8: dense 256->10 ; psp + output transpose
  dense8<<<47, 256, 0, stream>>>(U7, Wd4b, U8);
  psp8_out<<<1, 64, 0, stream>>>(U8, (float*)d_out);
}

// Round 3
// 1426.997 us; speedup vs baseline: 2.8469x; 1.1534x over previous
//
#include <hip/hip_runtime.h>

// SLAYER SNN forward, round 3: time-major [t][b][c][h][w] + restructured convs.
// Conv inner loop: per (ci,dy) hoist NCO*KS wave-uniform weights (pre-transposed
// [ci][dy][dx][co] -> contiguous s_load), lane computes NPX pixels via register
// sliding window (float2 LDS loads, even-aligned). LDS row strides swizzled
// (44/24/20) to spread banks. All fp32, IIR ordering bit-matches reference.

#define TT 300

#define A1 0.9048374180359595f   // exp(-1/10)
#define C1 0.2718281828459045f   // e/10
#define A2 0.36787944117144233f  // exp(-1)
#define C2 2.718281828459045f    // e
#define KREF (20.0f * C2)
#define THETA_F 10.0f

struct IIR {
  float p1, q1, p2, q2;
  __device__ IIR() : p1(0.f), q1(0.f), p2(0.f), q2(0.f) {}
  __device__ inline float step(float xin) {
    q1 = A1 * q1 + A1 * p1;
    float y = C1 * q1;
    p1 = A1 * p1 + xin;
    q2 = A2 * q2 + A2 * p2;
    float u = y - KREF * q2;
    float s = (u >= THETA_F) ? 1.0f : 0.0f;
    p2 = A2 * p2 + s;
    return s;
  }
};

// ---------------- generic tiled transpose: in[R][C] -> out[C][R] ----------------
__global__ __launch_bounds__(256) void transpose_rc(const float* __restrict__ in,
                                                    float* __restrict__ out,
                                                    int R, int C) {
  __shared__ float tile[64][65];
  int c0 = blockIdx.x * 64, r0 = blockIdx.y * 64;
  int tx = threadIdx.x & 63, ty = threadIdx.x >> 6;
  for (int i = ty; i < 64; i += 4) {
    int r = r0 + i, c = c0 + tx;
    if (r < R && c < C) tile[i][tx] = in[(long)r * C + c];
  }
  __syncthreads();
  for (int i = ty; i < 64; i += 4) {
    int c = c0 + i, r = r0 + tx;
    if (c < C && r < R) out[(long)c * R + r] = tile[tx][i];
  }
}

// ---------------- per-timestep conv, time-major, SGPR weights + reg window ----------------
// S: [T][B][CIN][HW][HW], Wt: [CIN][KS][KS][CO], U: [T][B][CO][HW][HW]
// block = 4 waves; wave w handles channels [cg*4*NCO + w*NCO, +NCO). lane -> (y, xg).
template <int CIN, int HW, int KS, int PAD, int CO, int NCO, int NPX, int RS, int NITER>
__global__ __launch_bounds__(256) void conv_tm2(const float* __restrict__ S,
                                                const float* __restrict__ Wt,
                                                float* __restrict__ U) {
  constexpr int PH = HW + 2 * PAD;
  constexpr int TILE = CIN * PH * RS;
  constexpr int XG = (HW + NPX - 1) / NPX;
  constexpr int SLOTS = HW * XG;
  constexpr int WIN = ((NPX + KS - 1) + 1) & ~1;  // even register window
  __shared__ float lin[TILE];
  const int t = blockIdx.x, b = blockIdx.y, B = gridDim.y;

  for (int i = threadIdx.x; i < TILE; i += 256) lin[i] = 0.f;
  __syncthreads();
  const float* src = S + ((long)t * B + b) * (CIN * HW * HW);
  for (int i = threadIdx.x; i < CIN * HW * HW; i += 256) {
    int ci = i / (HW * HW), r = i % (HW * HW);
    int iy = r / HW, ix = r % HW;
    lin[ci * PH * RS + (iy + PAD) * RS + ix + PAD] = src[i];
  }
  __syncthreads();

  const int lane = threadIdx.x & 63;
  const int co0 = blockIdx.z * (4 * NCO) +
                  __builtin_amdgcn_readfirstlane(threadIdx.x >> 6) * NCO;
  const float* wb = Wt + co0;

  for (int it = 0; it < NITER; ++it) {
    int slot = lane + 64 * it;
    bool act = slot < SLOTS;
    int ss = act ? slot : 0;
    int y = ss / XG, x0 = (ss % XG) * NPX;
    const float* base = lin + y * RS + x0;
    float acc[NCO][NPX];
#pragma unroll
    for (int j = 0; j < NCO; ++j)
#pragma unroll
      for (int px = 0; px < NPX; ++px) acc[j][px] = 0.f;

    for (int ci = 0; ci < CIN; ++ci) {
      const float* bp = base + ci * (PH * RS);
#pragma unroll
      for (int dy = 0; dy < KS; ++dy) {
        float wv[KS][NCO];
#pragma unroll
        for (int dx = 0; dx < KS; ++dx)
#pragma unroll
          for (int j = 0; j < NCO; ++j)
            wv[dx][j] = wb[(((ci * KS + dy) * KS + dx) * CO) + j];
        float win[WIN];
#pragma unroll
        for (int k = 0; k < WIN; k += 2) {
          float2 v = *(const float2*)(bp + dy * RS + k);
          win[k] = v.x; win[k + 1] = v.y;
        }
#pragma unroll
        for (int dx = 0; dx < KS; ++dx)
#pragma unroll
          for (int px = 0; px < NPX; ++px)
#pragma unroll
            for (int j = 0; j < NCO; ++j)
              acc[j][px] += wv[dx][j] * win[px + dx];
      }
    }
    if (act) {
      float* up = U + (((long)t * B + b) * CO + co0) * (HW * HW) + y * HW + x0;
#pragma unroll
      for (int j = 0; j < NCO; ++j)
#pragma unroll
        for (int px = 0; px < NPX; ++px)
          if (x0 + px < HW) up[j * (HW * HW) + px] = acc[j][px];
    }
  }
}

// ---------------- psp+spike, time-major, IN-PLACE ----------------
__global__ __launch_bounds__(256) void psp_spike_tm(float* __restrict__ io, int N) {
  int n = blockIdx.x * 256 + threadIdx.x;
  if (n >= N) return;
  IIR st;
  for (int t = 0; t < TT; ++t) {
    long idx = (long)t * N + n;
    io[idx] = st.step(io[idx]);
  }
}

// ---------------- 2x2 sum-pool (x11.0) + psp+spike, time-major ----------------
template <int C, int HIN, int HOUT>
__global__ __launch_bounds__(256) void pool_ps_tm(const float* __restrict__ sp,
                                                  float* __restrict__ out, int B) {
  const int NOUT = B * C * HOUT * HOUT;
  int n = blockIdx.x * 256 + threadIdx.x;
  if (n >= NOUT) return;
  int x = n % HOUT;
  int y = (n / HOUT) % HOUT;
  int c = (n / (HOUT * HOUT)) % C;
  int b = n / (C * HOUT * HOUT);
  bool hr = 2 * y + 1 < HIN, hc = 2 * x + 1 < HIN;
  const float* base = sp + ((long)b * C + c) * (HIN * HIN) + (2 * y) * HIN + 2 * x;
  const long SIN = (long)B * C * HIN * HIN;
  const long SOUT = NOUT;
  IIR st;
  for (int t = 0; t < TT; ++t) {
    const float* p = base + t * SIN;
    float a = p[0];
    if (hc) a += p[1];
    if (hr) {
      a += p[HIN];
      if (hc) a += p[HIN + 1];
    }
    out[t * SOUT + n] = st.step(11.0f * a);
  }
}

// ---------------- dense7: U[row][o] = sum_k S[row][k] * Wt[k][o] ----------------
__global__ __launch_bounds__(256) void dense7(const float* __restrict__ S,
                                              const float* __restrict__ Wt,
                                              float* __restrict__ U) {
  __shared__ float srow[4 * 2400];
  int r0 = blockIdx.x * 4;
  const float* src = S + (long)r0 * 2400;
  for (int i = threadIdx.x; i < 9600; i += 256) srow[i] = src[i];
  __syncthreads();
  int r = __builtin_amdgcn_readfirstlane(threadIdx.x >> 6);
  int o = (threadIdx.x & 63) * 4;
  const float* sr = srow + r * 2400;
  float4 acc = {0.f, 0.f, 0.f, 0.f};
  for (int k = 0; k < 2400; ++k) {
    float a = sr[k];
    float4 w = *(const float4*)(Wt + (long)k * 256 + o);
    acc.x += a * w.x; acc.y += a * w.y; acc.z += a * w.z; acc.w += a * w.w;
  }
  *(float4*)(U + (long)(r0 + r) * 256 + o) = acc;
}

// ---------------- dense8 ----------------
__global__ __launch_bounds__(256) void dense8(const float* __restrict__ S,
                                              const float* __restrict__ W,
                                              float* __restrict__ U) {
  int id = blockIdx.x * 256 + threadIdx.x;
  if (id >= 12000) return;
  int o = id % 10, row = id / 10;
  const float* sr = S + (long)row * 256;
  const float* wr = W + o * 256;
  float acc = 0.f;
  for (int k = 0; k < 256; ++k) acc += sr[k] * wr[k];
  U[id] = acc;
}

// ---------------- final psp+spike + transpose to (B,10,T) ----------------
__global__ void psp8_out(const float* __restrict__ U, float* __restrict__ out) {
  int n = threadIdx.x;
  if (n >= 40) return;
  IIR st;
  for (int t = 0; t < TT; ++t) out[n * TT + t] = st.step(U[t * 40 + n]);
}

extern "C" void kernel_launch(void* const* d_in, const int* in_sizes, int n_in,
                              void* d_out, int out_size, void* d_ws, size_t ws_size,
                              hipStream_t stream) {
  const float* s_in = (const float*)d_in[0];
  const float* Wc1  = (const float*)d_in[1];
  const float* Wc2  = (const float*)d_in[2];
  const float* Wc3  = (const float*)d_in[3];
  const float* Wd4a = (const float*)d_in[4];
  const float* Wd4b = (const float*)d_in[5];

  float* Buf1 = (float*)d_ws;            // 33,292,800 floats (U/spike for L1/L3/L5)
  float* Buf2 = Buf1 + 33292800;
  float* s2  = Buf2;                     //  8,323,200
  float* s4  = Buf2 + 8323200;           //  4,665,600
  float* Wt4a = Buf2 + 12988800;         //    614,400
  float* U7  = Buf2 + 13603200;          //    307,200 (becomes s7 in-place)
  float* T0  = Buf2 + 13910400;          //  2,774,400
  float* Wt1 = Buf2 + 16684800;          //      1,200
  float* Wt2 = Buf2 + 16686000;          //     10,368
  float* Wt3 = Buf2 + 16696368;          //     41,472
  float* s6  = Buf2;                     //  2,880,000 (s2 region, dead by L6)
  float* U8  = Buf1;                     //     12,000 (Buf1 dead by L8)

  // transposes: input -> time-major; weights -> [k][co] layouts
  transpose_rc<<<dim3(5, 145), 256, 0, stream>>>(s_in, T0, 9248, 300);
  transpose_rc<<<dim3(38, 4), 256, 0, stream>>>(Wd4a, Wt4a, 256, 2400);
  transpose_rc<<<dim3(1, 1), 256, 0, stream>>>(Wc1, Wt1, 24, 50);
  transpose_rc<<<dim3(4, 1), 256, 0, stream>>>(Wc2, Wt2, 48, 216);
  transpose_rc<<<dim3(7, 2), 256, 0, stream>>>(Wc3, Wt3, 96, 432);

  // L1: conv 2->24 k5 p2 (NCO=6, NPX=4, RS=44, NITER=5) ; psp in place
  conv_tm2<2, 34, 5, 2, 24, 6, 4, 44, 5><<<dim3(300, 4, 1), 256, 0, stream>>>(T0, Wt1, Buf1);
  psp_spike_tm<<<434, 256, 0, stream>>>(Buf1, 110976);
  // L2: pool 34->17 + IIR
  pool_ps_tm<24, 34, 17><<<109, 256, 0, stream>>>(Buf1, s2, 4);
  // L3: conv 24->48 k3 p1 (NCO=12, NPX=6, RS=24, NITER=1) ; psp in place
  conv_tm2<24, 17, 3, 1, 48, 12, 6, 24, 1><<<dim3(300, 4, 1), 256, 0, stream>>>(s2, Wt2, Buf1);
  psp_spike_tm<<<217, 256, 0, stream>>>(Buf1, 55488);
  // L4: pool 17->9 + IIR
  pool_ps_tm<48, 17, 9><<<61, 256, 0, stream>>>(Buf1, s4, 4);
  // L5: conv 48->96 k3 p1 (NCO=8, NPX=2, RS=20, NITER=1, 3 channel groups) ; psp
  conv_tm2<48, 9, 3, 1, 96, 8, 2, 20, 1><<<dim3(300, 4, 3), 256, 0, stream>>>(s4, Wt3, Buf1);
  psp_spike_tm<<<122, 256, 0, stream>>>(Buf1, 31104);
  // L6: pool 9->5 + IIR
  pool_ps_tm<96, 9, 5><<<38, 256, 0, stream>>>(Buf1, s6, 4);
  // L7: dense 2400->256 ; psp in place
  dense7<<<300, 256, 0, stream>>>(s6, Wt4a, U7);
  psp_spike_tm<<<4, 256, 0, stream>>>(U7, 1024);
  // L8: dense 256->10 ; psp + output transpose
  dense8<<<47, 256, 0, stream>>>(U7, Wd4b, U8);
  psp8_out<<<1, 64, 0, stream>>>(U8, (float*)d_out);
}

// Round 4
// 1035.466 us; speedup vs baseline: 3.9234x; 1.3781x over previous
//
#include <hip/hip_runtime.h>

// SLAYER SNN forward, round 4.
// - time-major [t][b][c][h][w] everywhere.
// - conv_tm3: odd LDS row strides (39/19/13) + scalar b32 window loads
//   (bank-conflict-free), SGPR weights, NPX-pixel register window per lane.
// - ppp_tm: fused psp+spike -> 2x2 pool (x11) -> psp+spike. One thread per
//   pooled neuron holds 4 input IIR states + 1 output IIR state; the
//   intermediate spike maps s1/s3/s5 are never materialized.
// All fp32; IIR op ordering bit-matches the reference scan.

#define TT 300

#define A1 0.9048374180359595f   // exp(-1/10)
#define C1 0.2718281828459045f   // e/10
#define A2 0.36787944117144233f  // exp(-1)
#define C2 2.718281828459045f    // e
#define KREF (20.0f * C2)
#define THETA_F 10.0f

struct IIR {
  float p1, q1, p2, q2;
  __device__ IIR() : p1(0.f), q1(0.f), p2(0.f), q2(0.f) {}
  __device__ inline float step(float xin) {
    q1 = A1 * q1 + A1 * p1;
    float y = C1 * q1;
    p1 = A1 * p1 + xin;
    q2 = A2 * q2 + A2 * p2;
    float u = y - KREF * q2;
    float s = (u >= THETA_F) ? 1.0f : 0.0f;
    p2 = A2 * p2 + s;
    return s;
  }
};

// ---------------- generic tiled transpose: in[R][C] -> out[C][R] ----------------
__global__ __launch_bounds__(256) void transpose_rc(const float* __restrict__ in,
                                                    float* __restrict__ out,
                                                    int R, int C) {
  __shared__ float tile[64][65];
  int c0 = blockIdx.x * 64, r0 = blockIdx.y * 64;
  int tx = threadIdx.x & 63, ty = threadIdx.x >> 6;
  for (int i = ty; i < 64; i += 4) {
    int r = r0 + i, c = c0 + tx;
    if (r < R && c < C) tile[i][tx] = in[(long)r * C + c];
  }
  __syncthreads();
  for (int i = ty; i < 64; i += 4) {
    int c = c0 + i, r = r0 + tx;
    if (c < C && r < R) out[(long)c * R + r] = tile[tx][i];
  }
}

// ---------------- conv-weight transposes, one launch ----------------
// Wc[co][k] -> Wt[k][co] for the three conv layers.
__global__ __launch_bounds__(256) void prep_w(const float* __restrict__ Wc1,
                                              const float* __restrict__ Wc2,
                                              const float* __restrict__ Wc3,
                                              float* __restrict__ Wt1,
                                              float* __restrict__ Wt2,
                                              float* __restrict__ Wt3) {
  int i = blockIdx.x * 256 + threadIdx.x;
  if (i < 1200) { int co = i / 50, k = i % 50; Wt1[k * 24 + co] = Wc1[i]; return; }
  i -= 1200;
  if (i < 10368) { int co = i / 216, k = i % 216; Wt2[k * 48 + co] = Wc2[i]; return; }
  i -= 10368;
  if (i < 41472) { int co = i / 432, k = i % 432; Wt3[k * 96 + co] = Wc3[i]; }
}

// ---------------- per-timestep conv, time-major ----------------
// S: [T][B][CIN][HW][HW], Wt: [CIN][KS][KS][CO], U: [T][B][CO][HW][HW]
// 4 waves/block; wave w -> channels [z*4*NCO + w*NCO, +NCO); lane -> (y, x-group).
template <int CIN, int HW, int KS, int PAD, int CO, int NCO, int NPX, int RS, int NITER>
__global__ __launch_bounds__(256) void conv_tm3(const float* __restrict__ S,
                                                const float* __restrict__ Wt,
                                                float* __restrict__ U) {
  constexpr int PH = HW + 2 * PAD;
  constexpr int TILE = CIN * PH * RS;
  constexpr int XG = (HW + NPX - 1) / NPX;
  constexpr int SLOTS = HW * XG;
  constexpr int WIN = NPX + KS - 1;
  __shared__ float lin[TILE + WIN];
  const int t = blockIdx.x, b = blockIdx.y, B = gridDim.y;

  for (int i = threadIdx.x; i < TILE + WIN; i += 256) lin[i] = 0.f;
  __syncthreads();
  const float* src = S + ((long)t * B + b) * (CIN * HW * HW);
  for (int i = threadIdx.x; i < CIN * HW * HW; i += 256) {
    int ci = i / (HW * HW), r = i % (HW * HW);
    int iy = r / HW, ix = r % HW;
    lin[ci * PH * RS + (iy + PAD) * RS + ix + PAD] = src[i];
  }
  __syncthreads();

  const int lane = threadIdx.x & 63;
  const int co0 = blockIdx.z * (4 * NCO) +
                  __builtin_amdgcn_readfirstlane(threadIdx.x >> 6) * NCO;
  const float* wb = Wt + co0;

  for (int it = 0; it < NITER; ++it) {
    int slot = lane + 64 * it;
    bool act = slot < SLOTS;
    int ss = act ? slot : 0;
    int y = ss / XG, x0 = (ss % XG) * NPX;
    const float* base = lin + y * RS + x0;
    float acc[NCO][NPX];
#pragma unroll
    for (int j = 0; j < NCO; ++j)
#pragma unroll
      for (int px = 0; px < NPX; ++px) acc[j][px] = 0.f;

    for (int ci = 0; ci < CIN; ++ci) {
      const float* bp = base + ci * (PH * RS);
#pragma unroll
      for (int dy = 0; dy < KS; ++dy) {
        float wv[KS][NCO];
#pragma unroll
        for (int dx = 0; dx < KS; ++dx)
#pragma unroll
          for (int j = 0; j < NCO; ++j)
            wv[dx][j] = wb[(((ci * KS + dy) * KS + dx) * CO) + j];
        float win[WIN];
#pragma unroll
        for (int k = 0; k < WIN; ++k) win[k] = bp[dy * RS + k];
#pragma unroll
        for (int dx = 0; dx < KS; ++dx)
#pragma unroll
          for (int px = 0; px < NPX; ++px)
#pragma unroll
            for (int j = 0; j < NCO; ++j)
              acc[j][px] += wv[dx][j] * win[px + dx];
      }
    }
    if (act) {
      float* up = U + (((long)t * B + b) * CO + co0) * (HW * HW) + y * HW + x0;
#pragma unroll
      for (int j = 0; j < NCO; ++j)
#pragma unroll
        for (int px = 0; px < NPX; ++px)
          if (x0 + px < HW) up[j * (HW * HW) + px] = acc[j][px];
    }
  }
}

// ---------------- fused psp+spike -> pool(2x2, x11) -> psp+spike ----------------
// U: [T][B][C][HIN][HIN] membrane inputs; out: [T][B][C][HOUT][HOUT] spikes.
template <int C, int HIN, int HOUT>
__global__ __launch_bounds__(256) void ppp_tm(const float* __restrict__ U,
                                              float* __restrict__ out, int B) {
  const int NOUT = B * C * HOUT * HOUT;
  const long SIN = (long)B * C * HIN * HIN;
  int n = blockIdx.x * 256 + threadIdx.x;
  if (n >= NOUT) return;
  int x2 = n % HOUT;
  int y2 = (n / HOUT) % HOUT;
  int c = (n / (HOUT * HOUT)) % C;
  int b = n / (C * HOUT * HOUT);
  const float* base = U + ((long)(b * C + c) * HIN + 2 * y2) * HIN + 2 * x2;
  IIR s00, s01, s10, s11, so;
  if constexpr (HIN % 2 == 0) {
    // all 2x2 windows fully valid; float2 loads are 8B-aligned and coalesced
    for (int t = 0; t < TT; ++t) {
      const float* p = base + (long)t * SIN;
      float2 r0 = *(const float2*)(p);
      float2 r1 = *(const float2*)(p + HIN);
      float sum = s00.step(r0.x) + s01.step(r0.y) + s10.step(r1.x) + s11.step(r1.y);
      out[(long)t * NOUT + n] = so.step(11.0f * sum);
    }
  } else {
    bool hr = 2 * y2 + 1 < HIN, hc = 2 * x2 + 1 < HIN;
    for (int t = 0; t < TT; ++t) {
      const float* p = base + (long)t * SIN;
      float a00 = p[0];
      float a01 = hc ? p[1] : 0.f;
      float a10 = hr ? p[HIN] : 0.f;
      float a11 = (hr && hc) ? p[HIN + 1] : 0.f;
      float sum = s00.step(a00) + s01.step(a01) + s10.step(a10) + s11.step(a11);
      out[(long)t * NOUT + n] = so.step(11.0f * sum);
    }
  }
}

// ---------------- psp+spike, time-major, IN-PLACE (small layers) ----------------
__global__ __launch_bounds__(256) void psp_spike_tm(float* __restrict__ io, int N) {
  int n = blockIdx.x * 256 + threadIdx.x;
  if (n >= N) return;
  IIR st;
  for (int t = 0; t < TT; ++t) {
    long idx = (long)t * N + n;
    io[idx] = st.step(io[idx]);
  }
}

// ---------------- dense7: U[row][o] = sum_k S[row][k] * Wt[k][o] ----------------
__global__ __launch_bounds__(256) void dense7(const float* __restrict__ S,
                                              const float* __restrict__ Wt,
                                              float* __restrict__ U) {
  __shared__ float srow[4 * 2400];
  int r0 = blockIdx.x * 4;
  const float* src = S + (long)r0 * 2400;
  for (int i = threadIdx.x; i < 9600; i += 256) srow[i] = src[i];
  __syncthreads();
  int r = __builtin_amdgcn_readfirstlane(threadIdx.x >> 6);
  int o = (threadIdx.x & 63) * 4;
  const float* sr = srow + r * 2400;
  float4 acc = {0.f, 0.f, 0.f, 0.f};
  for (int k = 0; k < 2400; ++k) {
    float a = sr[k];
    float4 w = *(const float4*)(Wt + (long)k * 256 + o);
    acc.x += a * w.x; acc.y += a * w.y; acc.z += a * w.z; acc.w += a * w.w;
  }
  *(float4*)(U + (long)(r0 + r) * 256 + o) = acc;
}

// ---------------- dense8 ----------------
__global__ __launch_bounds__(256) void dense8(const float* __restrict__ S,
                                              const float* __restrict__ W,
                                              float* __restrict__ U) {
  int id = blockIdx.x * 256 + threadIdx.x;
  if (id >= 12000) return;
  int o = id % 10, row = id / 10;
  const float* sr = S + (long)row * 256;
  const float* wr = W + o * 256;
  float acc = 0.f;
  for (int k = 0; k < 256; ++k) acc += sr[k] * wr[k];
  U[id] = acc;
}

// ---------------- final psp+spike + transpose to (B,10,T) ----------------
__global__ void psp8_out(const float* __restrict__ U, float* __restrict__ out) {
  int n = threadIdx.x;
  if (n >= 40) return;
  IIR st;
  for (int t = 0; t < TT; ++t) out[n * TT + t] = st.step(U[t * 40 + n]);
}

extern "C" void kernel_launch(void* const* d_in, const int* in_sizes, int n_in,
                              void* d_out, int out_size, void* d_ws, size_t ws_size,
                              hipStream_t stream) {
  const float* s_in = (const float*)d_in[0];
  const float* Wc1  = (const float*)d_in[1];
  const float* Wc2  = (const float*)d_in[2];
  const float* Wc3  = (const float*)d_in[3];
  const float* Wd4a = (const float*)d_in[4];
  const float* Wd4b = (const float*)d_in[5];

  float* Buf1 = (float*)d_ws;            // 33,292,800 floats (U1/U3/U5)
  float* Buf2 = Buf1 + 33292800;
  float* s2   = Buf2;                    //  8,323,200
  float* s4   = Buf2 + 8323200;          //  4,665,600
  float* Wt4a = Buf2 + 12988800;         //    614,400
  float* U7   = Buf2 + 13603200;         //    307,200 (becomes s7 in-place)
  float* T0   = Buf2 + 13910400;         //  2,774,400
  float* Wt1  = Buf2 + 16684800;         //      1,200
  float* Wt2  = Buf2 + 16686000;         //     10,368
  float* Wt3  = Buf2 + 16696368;         //     41,472
  float* s6   = Buf2;                    //  2,880,000 (s2 region, dead by L6)
  float* U8   = Buf1;                    //     12,000 (Buf1 dead by L8)

  // prep: input -> time-major; Wd4a -> [k][o]; conv weights -> [k][co]
  transpose_rc<<<dim3(5, 145), 256, 0, stream>>>(s_in, T0, 9248, 300);
  transpose_rc<<<dim3(38, 4), 256, 0, stream>>>(Wd4a, Wt4a, 256, 2400);
  prep_w<<<208, 256, 0, stream>>>(Wc1, Wc2, Wc3, Wt1, Wt2, Wt3);

  // L1: conv 2->24 k5 p2 (NCO=6, NPX=4, RS=39, NITER=5)
  conv_tm3<2, 34, 5, 2, 24, 6, 4, 39, 5><<<dim3(300, 4, 1), 256, 0, stream>>>(T0, Wt1, Buf1);
  // L1-psp + pool 34->17 + psp  -> s2
  ppp_tm<24, 34, 17><<<109, 256, 0, stream>>>(Buf1, s2, 4);
  // L3: conv 24->48 k3 p1 (NCO=12, NPX=6, RS=19, NITER=1)
  conv_tm3<24, 17, 3, 1, 48, 12, 6, 19, 1><<<dim3(300, 4, 1), 256, 0, stream>>>(s2, Wt2, Buf1);
  // L3-psp + pool 17->9 + psp -> s4
  ppp_tm<48, 17, 9><<<61, 256, 0, stream>>>(Buf1, s4, 4);
  // L5: conv 48->96 k3 p1 (NCO=12, NPX=2, RS=13, NITER=1, 2 channel groups)
  conv_tm3<48, 9, 3, 1, 96, 12, 2, 13, 1><<<dim3(300, 4, 2), 256, 0, stream>>>(s4, Wt3, Buf1);
  // L5-psp + pool 9->5 + psp -> s6
  ppp_tm<96, 9, 5><<<38, 256, 0, stream>>>(Buf1, s6, 4);
  // L7: dense 2400->256 ; psp in place
  dense7<<<300, 256, 0, stream>>>(s6, Wt4a, U7);
  psp_spike_tm<<<4, 256, 0, stream>>>(U7, 1024);
  // L8: dense 256->10 ; psp + output transpose
  dense8<<<47, 256, 0, stream>>>(U7, Wd4b, U8);
  psp8_out<<<1, 64, 0, stream>>>(U8, (float*)d_out);
}